// Round 5
// baseline (384.258 us; speedup 1.0000x reference)
//
#include <hip/hip_runtime.h>
#include <math.h>

// Problem constants: y is (8, 3, 256, 512) fp32, lmbd is (1,3).
#define TVW 512      // row length
#define TVH 256      // H (channel index = (row>>8)%3)
#define TVC 3
#define RPW 6        // rows per wave (active lanes 0..5); 6144/6 = 1024 waves = 1/SIMD
#define XSTR 516     // padded LDS stride for x rows: bank = (129*r + k)%32 spreads rows

// One row per LANE (6 active lanes per 64-wide wave; redundancy removed).
// The Condat state machine is run with select-based updates; the two rare-ish
// blocks (jump, terminate) are exec-masked. Register pipeline yn/yn1 plus
// caches x[km+1],x[km+2],x[kp+1],x[kp+2] (all pre-clamped to index<=511) mean
// a jump restarts from REGISTERS, never a dependent LDS gather. Flush writes
// go to a separate LDS out buffer (reads always see original y = exact
// reference semantics). 1024 waves -> every SIMD owns one wave; issue-bound.
__global__ __launch_bounds__(64)
void tv1d_lane_kernel(const float* __restrict__ y,
                      const float* __restrict__ lmbd,
                      float* __restrict__ out,
                      int total_rows) {
    __shared__ __align__(16) float xs[RPW * XSTR];  // original y rows (read-only)
    __shared__ __align__(16) float ob[RPW * TVW];   // output rows
    const int tid = threadIdx.x;                    // block == one wave
    const int base_row = blockIdx.x * RPW;
    const long n_elem = (long)total_rows * TVW;

    // ---- stage RPW rows (coalesced float4) into stride-XSTR layout ----
    {
        const float4* s4 = (const float4*)(y + (size_t)base_row * TVW);
        #pragma unroll
        for (int f4 = tid; f4 < RPW * TVW / 4; f4 += 64) {
            if ((long)base_row * TVW + f4 * 4 < n_elem) {
                float4 v = s4[f4];
                const int r = f4 >> 7;               // (f4*4)/512
                const int cc = (f4 & 127) << 2;
                float* d = xs + r * XSTR + cc;
                d[0] = v.x; d[1] = v.y; d[2] = v.z; d[3] = v.w;
            }
        }
    }
    __syncthreads();

    {
        const int lane = tid;
        const int row = base_row + lane;
        const bool active = (lane < RPW) && (row < total_rows);
        const float* x = xs + lane * XSTR;
        float* o = ob + lane * TVW;

        float lam = 0.0f;
        if (active) lam = log1pf(expf(lmbd[(row >> 8) % TVC]));
        const float nlam = -lam, twol = 2.0f * lam;

        // Condat state (reference tuple: k,k0,km,kp,umin,umax,vmin,vmax)
        int k = 0, k0 = 0, km = 0, kp = 0;
        float vmin = 0, vmax = 0, umin = lam, umax = nlam, denf = 1.0f;
        // pipeline: yn = x[min(k+1,511)], yn1 = x[min(k+2,511)]
        // caches:   xe1 = x[min(e+1,511)], xe2 = x[min(e+2,511)] for e in {km,kp}
        float yn = 0, yn1 = 0, xkm1 = 0, xkm2 = 0, xkp1 = 0, xkp2 = 0;
        if (active) {
            const float x0 = x[0];
            vmin = x0 - lam; vmax = x0 + lam;
            yn = x[1]; yn1 = x[2];
            xkm1 = yn; xkm2 = yn1; xkp1 = yn; xkp2 = yn1;
        }
        bool done = !active;

        for (int guard = 0; guard < 65536; ++guard) {
            if (__ballot(!done) == 0ull) break;     // wave-uniform exit
            if (!done) {
                const float ypre = x[k + 3 < TVW ? k + 3 : TVW - 1];  // prefetch
                const bool  atEnd  = (k == TVW - 1);
                const float umin_t = atEnd ? umin : umin + yn - vmin;
                const float umax_t = atEnd ? umax : umax + yn - vmax;
                const float tn = atEnd ? 0.0f : nlam;
                const float tp = atEnd ? 0.0f : lam;
                const bool negj = (umin_t < tn);
                const bool posj = !negj && (umax_t > tp);

                if (negj | posj) {
                    // ---- jump (covers b1/b2 mid-row and a1/a2 boundary) ----
                    const int   e  = negj ? km : kp;
                    const float fv = negj ? vmin : vmax;
                    const int   pe = e < TVW - 1 ? e : TVW - 1;
                    for (int p = k0; p <= pe; ++p) o[p] = fv;   // masked flush
                    const int k0n = e + 1;
                    const float newv = negj ? xkm1 : xkp1;      // x[min(k0n,511)]
                    const float nyn  = negj ? xkm2 : xkp2;      // x[min(k0n+1,511)]
                    const float nyn1 = x[k0n + 2 < TVW ? k0n + 2 : TVW - 1];
                    const bool bmid = !atEnd;
                    const float ovmin = vmin, ovmax = vmax;
                    vmin = negj ? newv : (bmid ? newv - twol : ovmin);
                    vmax = posj ? newv : (bmid ? newv + twol : ovmax);
                    umin = (posj && atEnd) ? (newv - lam - ovmin) : lam;
                    umax = (negj && atEnd) ? (newv + lam - ovmax) : nlam;
                    if (negj || bmid) { km = k0n; xkm1 = nyn; xkm2 = nyn1; }
                    if (posj || bmid) { kp = k0n; xkp1 = nyn; xkp2 = nyn1; }
                    k = k0n; k0 = k0n; denf = 1.0f;
                    yn = nyn; yn1 = nyn1;
                } else if (atEnd) {
                    // ---- a3 terminate: flush [k0..511] at segment mean ----
                    const float v = vmin + umin * __builtin_amdgcn_rcpf(denf);
                    for (int p = k0; p < TVW; ++p) o[p] = v;
                    done = true;
                } else {
                    // ---- b3 extend (branchless hit updates) ----
                    const int kn = k + 1;
                    denf += 1.0f;
                    const float r = __builtin_amdgcn_rcpf(denf);
                    const bool hm = (umin_t >= lam);
                    const bool hp = (umax_t <= nlam);
                    vmin = fmaf(fmaxf(umin_t - lam, 0.0f), r, vmin);
                    vmax = fmaf(fminf(umax_t + lam, 0.0f), r, vmax);
                    umin = fminf(umin_t, lam);
                    umax = fmaxf(umax_t, nlam);
                    if (hm) { km = kn; xkm1 = yn1; xkm2 = ypre; }
                    if (hp) { kp = kn; xkp1 = yn1; xkp2 = ypre; }
                    k = kn; yn = yn1; yn1 = ypre;
                }
            }
        }
    }
    __syncthreads();

    // ---- coalesced float4 writeback ob -> out ----
    {
        float4* d4 = (float4*)(out + (size_t)base_row * TVW);
        const float4* s4 = (const float4*)ob;
        #pragma unroll
        for (int f4 = tid; f4 < RPW * TVW / 4; f4 += 64)
            if ((long)base_row * TVW + f4 * 4 < n_elem)
                d4[f4] = s4[f4];
    }
}

extern "C" void kernel_launch(void* const* d_in, const int* in_sizes, int n_in,
                              void* d_out, int out_size, void* d_ws, size_t ws_size,
                              hipStream_t stream) {
    const float* y    = (const float*)d_in[0];
    const float* lmbd = (const float*)d_in[1];
    float* out = (float*)d_out;

    const int total_rows = in_sizes[0] / TVW;              // 6144
    const int grid = (total_rows + RPW - 1) / RPW;         // 1024 blocks (1 wave each)
    tv1d_lane_kernel<<<grid, 64, 0, stream>>>(y, lmbd, out, total_rows);
}

// Round 6
// 319.146 us; speedup vs baseline: 1.2040x; 1.2040x over previous
//
#include <hip/hip_runtime.h>
#include <math.h>

// Problem constants: y is (8, 3, 256, 512) fp32, lmbd is (1,3).
#define TVW 512      // row length
#define TVC 3        // channels; channel = (row >> 8) % 3
#define RPWAVE 2     // rows per wave (groups of 32 lanes)
#define WAVES 4      // waves per block
#define RPB (RPWAVE * WAVES)   // 8 rows per block
#define BLOCK (WAVES * 64)     // 256 threads
#define G 32         // lanes per row group

// Sub-wave grouping: each 64-lane wave runs TWO rows, 32 redundant lanes per
// row. 6144 rows -> 3072 waves = 3 waves/SIMD (latency hiding), each
// wave-inst serves 2 rows (vs 1 in the round-4 fully-redundant version), and
// flush loops fan 32 lanes across the segment (vs 1 elem/iter in round 5).
// State machine is the validated round-5 select-based body: extend path
// branchless, jump+boundary folded into one exec-masked block, register
// caches x[km+1],x[km+2],x[kp+1],x[kp+2] so jumps restart from registers.
// Within a group all LDS reads are broadcasts; across the two groups at most
// 2-way bank aliasing (free).
__global__ __launch_bounds__(BLOCK)
void tv1d_group_kernel(const float* __restrict__ y,
                       const float* __restrict__ lmbd,
                       float* __restrict__ out,
                       int total_rows) {
    __shared__ __align__(16) float xs[RPB * TVW];   // original y (read-only)
    __shared__ __align__(16) float ob[RPB * TVW];   // output rows
    const int tid = threadIdx.x;
    const int base_row = blockIdx.x * RPB;

    // ---- stage 8 contiguous rows into LDS, coalesced float4 ----
    {
        const float4* s4 = (const float4*)(y + (size_t)base_row * TVW);
        float4* d4 = (float4*)xs;
        #pragma unroll
        for (int i = tid; i < RPB * TVW / 4; i += BLOCK)
            d4[i] = s4[i];
    }
    __syncthreads();

    {
        const int wave = tid >> 6;
        const int lane = tid & 63;
        const int sub  = lane >> 5;          // which of the wave's 2 rows
        const int g    = lane & 31;          // position within the 32-lane group
        const int lrow = wave * RPWAVE + sub;
        const int row  = base_row + lrow;
        const bool active = row < total_rows;
        const float* x = xs + lrow * TVW;
        float* o = ob + lrow * TVW;

        float lam = 0.0f;
        if (active) lam = log1pf(expf(lmbd[(row >> 8) % TVC]));
        const float nlam = -lam, twol = 2.0f * lam;

        // Condat state (reference tuple: k,k0,km,kp,umin,umax,vmin,vmax)
        int k = 0, k0 = 0, km = 0, kp = 0;
        float vmin = 0, vmax = 0, umin = lam, umax = nlam, denf = 1.0f;
        // pipeline: yn = x[min(k+1,511)], yn1 = x[min(k+2,511)]
        // caches:   xe1 = x[min(e+1,511)], xe2 = x[min(e+2,511)], e in {km,kp}
        float yn = 0, yn1 = 0, xkm1 = 0, xkm2 = 0, xkp1 = 0, xkp2 = 0;
        if (active) {
            const float x0 = x[0];
            vmin = x0 - lam; vmax = x0 + lam;
            yn = x[1]; yn1 = x[2];
            xkm1 = yn; xkm2 = yn1; xkp1 = yn; xkp2 = yn1;
        }
        bool done = !active;

        for (int guard = 0; guard < 65536; ++guard) {
            if (__ballot(!done) == 0ull) break;     // wave-uniform exit
            if (!done) {
                const float ypre = x[k + 3 < TVW ? k + 3 : TVW - 1];  // prefetch
                const bool  atEnd  = (k == TVW - 1);
                const float umin_t = atEnd ? umin : umin + yn - vmin;
                const float umax_t = atEnd ? umax : umax + yn - vmax;
                const float tn = atEnd ? 0.0f : nlam;
                const float tp = atEnd ? 0.0f : lam;
                const bool negj = (umin_t < tn);
                const bool posj = !negj && (umax_t > tp);

                if (negj | posj) {
                    // ---- jump (covers b1/b2 mid-row and a1/a2 boundary) ----
                    const int   e  = negj ? km : kp;
                    const float fv = negj ? vmin : vmax;
                    const int   pe = e < TVW - 1 ? e : TVW - 1;
                    for (int p = k0 + g; p <= pe; p += G) o[p] = fv;  // group flush
                    const int k0n = e + 1;
                    const float newv = negj ? xkm1 : xkp1;      // x[min(k0n,511)]
                    const float nyn  = negj ? xkm2 : xkp2;      // x[min(k0n+1,511)]
                    const float nyn1 = x[k0n + 2 < TVW ? k0n + 2 : TVW - 1];
                    const bool bmid = !atEnd;
                    const float ovmin = vmin, ovmax = vmax;
                    vmin = negj ? newv : (bmid ? newv - twol : ovmin);
                    vmax = posj ? newv : (bmid ? newv + twol : ovmax);
                    umin = (posj && atEnd) ? (newv - lam - ovmin) : lam;
                    umax = (negj && atEnd) ? (newv + lam - ovmax) : nlam;
                    if (negj || bmid) { km = k0n; xkm1 = nyn; xkm2 = nyn1; }
                    if (posj || bmid) { kp = k0n; xkp1 = nyn; xkp2 = nyn1; }
                    k = k0n; k0 = k0n; denf = 1.0f;
                    yn = nyn; yn1 = nyn1;
                } else if (atEnd) {
                    // ---- a3 terminate: flush [k0..511] at segment mean ----
                    const float v = vmin + umin * __builtin_amdgcn_rcpf(denf);
                    for (int p = k0 + g; p < TVW; p += G) o[p] = v;
                    done = true;
                } else {
                    // ---- b3 extend (branchless hit updates) ----
                    const int kn = k + 1;
                    denf += 1.0f;
                    const float r = __builtin_amdgcn_rcpf(denf);
                    const bool hm = (umin_t >= lam);
                    const bool hp = (umax_t <= nlam);
                    vmin = fmaf(fmaxf(umin_t - lam, 0.0f), r, vmin);
                    vmax = fmaf(fminf(umax_t + lam, 0.0f), r, vmax);
                    umin = fminf(umin_t, lam);
                    umax = fmaxf(umax_t, nlam);
                    if (hm) { km = kn; xkm1 = yn1; xkm2 = ypre; }
                    if (hp) { kp = kn; xkp1 = yn1; xkp2 = ypre; }
                    k = kn; yn = yn1; yn1 = ypre;
                }
            }
        }
    }
    __syncthreads();

    // ---- coalesced float4 writeback ob -> out ----
    {
        float4* d4 = (float4*)(out + (size_t)base_row * TVW);
        const float4* s4 = (const float4*)ob;
        #pragma unroll
        for (int i = tid; i < RPB * TVW / 4; i += BLOCK)
            d4[i] = s4[i];
    }
}

extern "C" void kernel_launch(void* const* d_in, const int* in_sizes, int n_in,
                              void* d_out, int out_size, void* d_ws, size_t ws_size,
                              hipStream_t stream) {
    const float* y    = (const float*)d_in[0];
    const float* lmbd = (const float*)d_in[1];
    float* out = (float*)d_out;

    const int total_rows = in_sizes[0] / TVW;          // 6144
    const int grid = (total_rows + RPB - 1) / RPB;     // 768 blocks (4 waves each)
    tv1d_group_kernel<<<grid, BLOCK, 0, stream>>>(y, lmbd, out, total_rows);
}